// Round 7
// baseline (5426.685 us; speedup 1.0000x reference)
//
#include <hip/hip_runtime.h>
#include <stdint.h>

typedef _Float16 f16;
typedef unsigned short u16;

#define NDIM  4096
#define KDIM  4096
#define LRDIM 64

__device__ __forceinline__ float bf2f(u16 b) {
  union { unsigned u; float f; } c; c.u = ((unsigned)b) << 16; return c.f;
}
__device__ __forceinline__ float h2f(u16 b) {
  union { u16 u; f16 h; } c; c.u = b; return (float)c.h;
}
__device__ __forceinline__ short f2h(float v) {
  union { f16 h; short s; } c; c.h = (f16)v; return c.s;
}

// ---------------------------------------------------------------------------
// frozen encoding classifier: 0 = f16 halfwords, 1 = bf16 halfwords, 2 = f32.
// Samples the first 4096 halfwords. Even/odd in-range fractions (bf16-decode
// in [0.05,10]): f32 data -> (0.03, 0.96); bf16 -> (0.96, 0.96); f16 -> (0.2,
// 0.2). All 256 threads must call before any divergence.
// ---------------------------------------------------------------------------
__device__ int frozen_mode(const void* frozen, int t) {
  const u16* fr = (const u16*)frozen;
  __shared__ int sE[256], sO[256];
  int ce = 0, co = 0;
  for (int j = 0; j < 8; ++j) {
    float ve = fabsf(bf2f(fr[t * 16 + 2 * j]));
    float vo = fabsf(bf2f(fr[t * 16 + 2 * j + 1]));
    if (ve >= 0.05f && ve <= 10.0f) ++ce;
    if (vo >= 0.05f && vo <= 10.0f) ++co;
  }
  sE[t] = ce; sO[t] = co;
  __syncthreads();
  for (int s = 128; s > 0; s >>= 1) {
    if (t < s) { sE[t] += sE[t + s]; sO[t] += sO[t + s]; }
    __syncthreads();
  }
  int te = sE[0], to = sO[0];
  __syncthreads();
  if (to > 1024) return (te > 1024) ? 1 : 2;
  return 0;
}

__device__ __forceinline__ float dec_frozen(const void* fr, size_t idx, int mode) {
  if (mode == 2) return ((const float*)fr)[idx];
  u16 b = ((const u16*)fr)[idx];
  return (mode == 1) ? bf2f(b) : h2f(b);
}

// ---------------------------------------------------------------------------
// k7_build_m: mW[o][i] = f16( gb[o/8][i/8] + frozen[o][i]*gs[o/8][i/8]
//                             + sa[o][i] ), stored as f16 bits.
// ---------------------------------------------------------------------------
__global__ __launch_bounds__(256) void k7_build_m(
    const void* __restrict__ frozen, const float* __restrict__ gs,
    const float* __restrict__ gb, const float* __restrict__ sa,
    short* __restrict__ mW)
{
  int mode = frozen_mode(frozen, threadIdx.x);
  int idx = blockIdx.x * 256 + threadIdx.x;   // 2,097,152 threads, 8 elems each
  int o  = idx >> 9;
  int ig = idx & 511;
  size_t base = (size_t)o * KDIM + ig * 8;
  int gidx = (o >> 3) * 512 + ig;
  float gsf = gs[gidx], gbf = gb[gidx];
#pragma unroll
  for (int j = 0; j < 8; ++j) {
    float fv = dec_frozen(frozen, base + j, mode);
    mW[base + j] = f2h(gbf + fv * gsf + sa[base + j]);
  }
}

// ---------------------------------------------------------------------------
// k7_hid: hid[8192][64] = x @ L1^T (f32 acc, f16 store). 128 blocks.
// ---------------------------------------------------------------------------
__global__ __launch_bounds__(256) void k7_hid(const float* __restrict__ x,
                                              const float* __restrict__ L1,
                                              short* __restrict__ hid)
{
  __shared__ float sA[64 * 33];
  __shared__ float sB[64 * 33];
  int t = threadIdx.x;
  int brow = blockIdx.x * 64;
  int tr = t >> 4, tc = t & 15;
  float acc[4][4] = {};

  for (int kt = 0; kt < KDIM / 32; ++kt) {
    __syncthreads();
    for (int j = 0; j < 8; ++j) {
      int u = t * 8 + j;
      int r = u >> 5, c = u & 31;
      sA[r * 33 + c] = x[(size_t)(brow + r) * KDIM + kt * 32 + c];
      sB[r * 33 + c] = L1[(size_t)r * KDIM + kt * 32 + c];
    }
    __syncthreads();
    for (int kk = 0; kk < 32; ++kk) {
      float a[4], b[4];
#pragma unroll
      for (int i = 0; i < 4; ++i) a[i] = sA[(tr * 4 + i) * 33 + kk];
#pragma unroll
      for (int j = 0; j < 4; ++j) b[j] = sB[(tc * 4 + j) * 33 + kk];
#pragma unroll
      for (int i = 0; i < 4; ++i)
#pragma unroll
        for (int j = 0; j < 4; ++j) acc[i][j] += a[i] * b[j];
    }
  }
#pragma unroll
  for (int i = 0; i < 4; ++i)
#pragma unroll
    for (int j = 0; j < 4; ++j)
      hid[(size_t)(brow + tr * 4 + i) * LRDIM + tc * 4 + j] = f2h(acc[i][j]);
}

// ---------------------------------------------------------------------------
// k7_main<PRE,HIDWS>: baseline = x @ m^T; mul = hid @ L2[0:4096]^T + scale;
// add = hid @ L2[4096:8192]^T + bias; out = add + mul*baseline.
// m from ws (PRE) or recomputed in-tile; hid from ws (HIDWS) or recomputed.
// 64x64 tiles, 8192 blocks, 256 threads (4x4 outputs each).
// ---------------------------------------------------------------------------
template<bool PRE, bool HIDWS>
__global__ __launch_bounds__(256) void k7_main(
    const float* __restrict__ x, const short* __restrict__ mW,
    const void* __restrict__ frozen, const float* __restrict__ gs,
    const float* __restrict__ gb, const float* __restrict__ sa,
    const short* __restrict__ hid, const float* __restrict__ L1,
    const float* __restrict__ L2, const float* __restrict__ scale,
    const float* __restrict__ bias, float* __restrict__ out)
{
  __shared__ float sA[64 * 65];
  __shared__ float sB[64 * 65];
  int t = threadIdx.x;
  int tr = t >> 4, tc = t & 15;
  int bm = blockIdx.x >> 6;       // 128 m-tiles
  int bn = blockIdx.x & 63;       // 64 n-tiles
  int brow = bm * 64, bcol = bn * 64;

  int mode = 0;
  if constexpr (!PRE) mode = frozen_mode(frozen, t);

  float acc[4][4] = {};           // baseline

  for (int kt = 0; kt < KDIM / 32; ++kt) {
    __syncthreads();
    for (int j = 0; j < 8; ++j) {
      int u = t * 8 + j;
      int r = u >> 5, c = u & 31;
      sA[r * 65 + c] = x[(size_t)(brow + r) * KDIM + kt * 32 + c];
      if constexpr (PRE) {
        sB[r * 65 + c] = h2f((u16)mW[(size_t)(bcol + r) * KDIM + kt * 32 + c]);
      } else {
        int o = bcol + r, i = kt * 32 + c;
        int gidx = (o >> 3) * 512 + (i >> 3);
        float fv = dec_frozen(frozen, (size_t)o * KDIM + i, mode);
        sB[r * 65 + c] = gb[gidx] + fv * gs[gidx] + sa[(size_t)o * KDIM + i];
      }
    }
    __syncthreads();
    for (int kk = 0; kk < 32; ++kk) {
      float a[4], b[4];
#pragma unroll
      for (int i = 0; i < 4; ++i) a[i] = sA[(tr * 4 + i) * 65 + kk];
#pragma unroll
      for (int j = 0; j < 4; ++j) b[j] = sB[(tc * 4 + j) * 65 + kk];
#pragma unroll
      for (int i = 0; i < 4; ++i)
#pragma unroll
        for (int j = 0; j < 4; ++j) acc[i][j] += a[i] * b[j];
    }
  }

  // ---- hid tile (rows brow..brow+63, 64 cols) ----
  float hacc[4][4] = {};
  if constexpr (!HIDWS) {
    for (int kt = 0; kt < KDIM / 32; ++kt) {
      __syncthreads();
      for (int j = 0; j < 8; ++j) {
        int u = t * 8 + j;
        int r = u >> 5, c = u & 31;
        sA[r * 65 + c] = x[(size_t)(brow + r) * KDIM + kt * 32 + c];
        sB[r * 65 + c] = L1[(size_t)r * KDIM + kt * 32 + c];
      }
      __syncthreads();
      for (int kk = 0; kk < 32; ++kk) {
        float a[4], b[4];
#pragma unroll
        for (int i = 0; i < 4; ++i) a[i] = sA[(tr * 4 + i) * 65 + kk];
#pragma unroll
        for (int j = 0; j < 4; ++j) b[j] = sB[(tc * 4 + j) * 65 + kk];
#pragma unroll
        for (int i = 0; i < 4; ++i)
#pragma unroll
          for (int j = 0; j < 4; ++j) hacc[i][j] += a[i] * b[j];
      }
    }
  }

  __syncthreads();
  if constexpr (HIDWS) {
    for (int j = 0; j < 16; ++j) {
      int u = t * 16 + j;
      int r = u >> 6, c = u & 63;
      sA[r * 65 + c] = h2f((u16)hid[(size_t)(brow + r) * LRDIM + c]);
      sB[r * 65 + c] = L2[(size_t)(bcol + r) * LRDIM + c];
    }
  } else {
#pragma unroll
    for (int i = 0; i < 4; ++i)
#pragma unroll
      for (int j = 0; j < 4; ++j)
        sA[(tr * 4 + i) * 65 + tc * 4 + j] = hacc[i][j];
    for (int j = 0; j < 16; ++j) {
      int u = t * 16 + j;
      int r = u >> 6, c = u & 63;
      sB[r * 65 + c] = L2[(size_t)(bcol + r) * LRDIM + c];
    }
  }
  __syncthreads();

  float sc[4], bi[4];
#pragma unroll
  for (int j = 0; j < 4; ++j) {
    int o = bcol + tc * 4 + j;
    sc[j] = scale[o];
    bi[j] = bias[o];
  }

  float macc[4][4];
#pragma unroll
  for (int i = 0; i < 4; ++i)
#pragma unroll
    for (int j = 0; j < 4; ++j) macc[i][j] = sc[j];
  for (int kk = 0; kk < 64; ++kk) {
    float a[4], b[4];
#pragma unroll
    for (int i = 0; i < 4; ++i) a[i] = sA[(tr * 4 + i) * 65 + kk];
#pragma unroll
    for (int j = 0; j < 4; ++j) b[j] = sB[(tc * 4 + j) * 65 + kk];
#pragma unroll
    for (int i = 0; i < 4; ++i)
#pragma unroll
      for (int j = 0; j < 4; ++j) macc[i][j] += a[i] * b[j];
  }

  __syncthreads();
  for (int j = 0; j < 16; ++j) {
    int u = t * 16 + j;
    int r = u >> 6, c = u & 63;
    sB[r * 65 + c] = L2[(size_t)(NDIM + bcol + r) * LRDIM + c];
  }
  __syncthreads();

  float aacc[4][4];
#pragma unroll
  for (int i = 0; i < 4; ++i)
#pragma unroll
    for (int j = 0; j < 4; ++j) aacc[i][j] = bi[j];
  for (int kk = 0; kk < 64; ++kk) {
    float a[4], b[4];
#pragma unroll
    for (int i = 0; i < 4; ++i) a[i] = sA[(tr * 4 + i) * 65 + kk];
#pragma unroll
    for (int j = 0; j < 4; ++j) b[j] = sB[(tc * 4 + j) * 65 + kk];
#pragma unroll
    for (int i = 0; i < 4; ++i)
#pragma unroll
      for (int j = 0; j < 4; ++j) aacc[i][j] += a[i] * b[j];
  }

#pragma unroll
  for (int i = 0; i < 4; ++i) {
    size_t row = (size_t)(brow + tr * 4 + i);
#pragma unroll
    for (int j = 0; j < 4; ++j) {
      int col = bcol + tc * 4 + j;
      out[row * NDIM + col] = aacc[i][j] + macc[i][j] * acc[i][j];
    }
  }
}

// ---------------------------------------------------------------------------
extern "C" void kernel_launch(void* const* d_in, const int* in_sizes, int n_in,
                              void* d_out, int out_size, void* d_ws, size_t ws_size,
                              hipStream_t stream)
{
  // Expected element-count signatures.
  const int SD[9] = {33554432,16777216,262144,524288,262144,262144,16777216,4096,4096};
  const int SA[9] = {4096,16777216,262144,262144,262144,524288,4096,16777216,33554432};
  bool dict = (n_in == 9), alph = (n_in == 9);
  if (n_in == 9) {
    for (int i = 0; i < 9; ++i) {
      if (in_sizes[i] != SD[i]) dict = false;
      if (in_sizes[i] != SA[i]) alph = false;
    }
  }
  if (!dict && !alph) {
    // fallback: locate x by size; assume dict-like otherwise
    int ix = 0;
    for (int i = 0; i < n_in; ++i)
      if (in_sizes[i] == 33554432 || in_sizes[i] == 134217728) { ix = i; break; }
    dict = (ix == 0);
    alph = !dict;
  }
  const float* x     = (const float*)d_in[dict ? 0 : 8];
  const void*  fr    =               d_in[1];
  const float* L1    = (const float*)d_in[dict ? 2 : 4];
  const float* L2    = (const float*)d_in[dict ? 3 : 5];
  const float* gs    = (const float*)d_in[dict ? 4 : 3];
  const float* gb    = (const float*)d_in[dict ? 5 : 2];
  const float* sa    = (const float*)d_in[dict ? 6 : 7];
  const float* scale = (const float*)d_in[dict ? 7 : 6];
  const float* bias  = (const float*)d_in[dict ? 8 : 0];
  float* out = (float*)d_out;

  const size_t MW_B  = (size_t)NDIM * KDIM * 2;   // 33,554,432
  const size_t HID_B = (size_t)8192 * LRDIM * 2;  //  1,048,576
  bool pre  = ws_size >= MW_B + HID_B;
  bool hidw = pre || ws_size >= HID_B;

  char* ws = (char*)d_ws;
  short* mW  = (short*)ws;
  short* hid = (short*)(ws + (pre ? MW_B : 0));

  if (pre)
    k7_build_m<<<dim3(8192), dim3(256), 0, stream>>>(fr, gs, gb, sa, mW);
  if (hidw)
    k7_hid<<<dim3(128), dim3(256), 0, stream>>>(x, L1, hid);

  if (pre)
    k7_main<true, true><<<dim3(8192), dim3(256), 0, stream>>>(
        x, mW, fr, gs, gb, sa, hid, L1, L2, scale, bias, out);
  else if (hidw)
    k7_main<false, true><<<dim3(8192), dim3(256), 0, stream>>>(
        x, mW, fr, gs, gb, sa, hid, L1, L2, scale, bias, out);
  else
    k7_main<false, false><<<dim3(8192), dim3(256), 0, stream>>>(
        x, mW, fr, gs, gb, sa, hid, L1, L2, scale, bias, out);
}

// Round 8
// 1737.971 us; speedup vs baseline: 3.1224x; 3.1224x over previous
//
#include <hip/hip_runtime.h>
#include <stdint.h>

typedef _Float16 f16;
typedef unsigned short u16;
typedef __attribute__((ext_vector_type(8))) _Float16 h16x8;
typedef __attribute__((ext_vector_type(8))) unsigned short u16x8;
typedef __attribute__((ext_vector_type(4))) float f32x4;

#define NDIM  4096
#define KDIM  4096
#define LRDIM 64

__device__ __forceinline__ float bf2f(u16 b) {
  union { unsigned u; float f; } c; c.u = ((unsigned)b) << 16; return c.f;
}
__device__ __forceinline__ float h2f(u16 b) {
  union { u16 u; f16 h; } c; c.u = b; return (float)c.h;
}
__device__ __forceinline__ short f2h(float v) {
  union { f16 h; short s; } c; c.h = (f16)v; return c.s;
}
__device__ __forceinline__ h16x8 pack8(float4 a, float4 b) {
  h16x8 w = { (f16)a.x, (f16)a.y, (f16)a.z, (f16)a.w,
              (f16)b.x, (f16)b.y, (f16)b.z, (f16)b.w };
  return w;
}

// ---------------------------------------------------------------------------
// frozen encoding classifier: 0 = f16 halfwords, 1 = bf16 halfwords, 2 = f32.
// Even/odd in-range fractions of bf16-decodes over first 4096 halfwords.
// All 256 threads must call before any divergence.
// ---------------------------------------------------------------------------
__device__ int frozen_mode(const void* frozen, int t) {
  const u16* fr = (const u16*)frozen;
  __shared__ int sE[256], sO[256];
  int ce = 0, co = 0;
  for (int j = 0; j < 8; ++j) {
    float ve = fabsf(bf2f(fr[t * 16 + 2 * j]));
    float vo = fabsf(bf2f(fr[t * 16 + 2 * j + 1]));
    if (ve >= 0.05f && ve <= 10.0f) ++ce;
    if (vo >= 0.05f && vo <= 10.0f) ++co;
  }
  sE[t] = ce; sO[t] = co;
  __syncthreads();
  for (int s = 128; s > 0; s >>= 1) {
    if (t < s) { sE[t] += sE[t + s]; sO[t] += sO[t + s]; }
    __syncthreads();
  }
  int te = sE[0], to = sO[0];
  __syncthreads();
  if (to > 1024) return (te > 1024) ? 1 : 2;
  return 0;
}

__device__ __forceinline__ float dec_frozen(const void* fr, size_t idx, int mode) {
  if (mode == 2) return ((const float*)fr)[idx];
  u16 b = ((const u16*)fr)[idx];
  return (mode == 1) ? bf2f(b) : h2f(b);
}

// Build 8 consecutive m elements (row o, cols i0..i0+7) as f16x8.
__device__ __forceinline__ h16x8 build_m8(
    const void* __restrict__ frozen, const float* __restrict__ gs,
    const float* __restrict__ gb, const float* __restrict__ sa,
    int o, int i0, int mode)
{
  size_t fo = (size_t)o * KDIM + i0;
  int gidx = (o >> 3) * 512 + (i0 >> 3);
  float gsf = gs[gidx], gbf = gb[gidx];
  float4 s0 = ((const float4*)(sa + fo))[0];
  float4 s1 = ((const float4*)(sa + fo))[1];
  float sv[8] = { s0.x, s0.y, s0.z, s0.w, s1.x, s1.y, s1.z, s1.w };
  float fv[8];
  if (mode == 2) {
    float4 q0 = ((const float4*)((const float*)frozen + fo))[0];
    float4 q1 = ((const float4*)((const float*)frozen + fo))[1];
    fv[0]=q0.x; fv[1]=q0.y; fv[2]=q0.z; fv[3]=q0.w;
    fv[4]=q1.x; fv[5]=q1.y; fv[6]=q1.z; fv[7]=q1.w;
  } else {
    u16x8 fb = *(const u16x8*)((const u16*)frozen + fo);
#pragma unroll
    for (int j = 0; j < 8; ++j) fv[j] = (mode == 1) ? bf2f(fb[j]) : h2f(fb[j]);
  }
  h16x8 w;
#pragma unroll
  for (int j = 0; j < 8; ++j) w[j] = (f16)(gbf + fv[j] * gsf + sv[j]);
  return w;
}

// ---------------------------------------------------------------------------
// k8_flag: classify frozen encoding once; store to ws.
// ---------------------------------------------------------------------------
__global__ __launch_bounds__(256) void k8_flag(const void* __restrict__ fr,
                                               int* __restrict__ flag)
{
  int m = frozen_mode(fr, threadIdx.x);
  if (threadIdx.x == 0) *flag = m;
}

// ---------------------------------------------------------------------------
// k7_hid: hid[8192][64] = x @ L1^T (f32 acc, f16 store). 128 blocks. (proven)
// ---------------------------------------------------------------------------
__global__ __launch_bounds__(256) void k7_hid(const float* __restrict__ x,
                                              const float* __restrict__ L1,
                                              short* __restrict__ hid)
{
  __shared__ float sA[64 * 33];
  __shared__ float sB[64 * 33];
  int t = threadIdx.x;
  int brow = blockIdx.x * 64;
  int tr = t >> 4, tc = t & 15;
  float acc[4][4] = {};

  for (int kt = 0; kt < KDIM / 32; ++kt) {
    __syncthreads();
    for (int j = 0; j < 8; ++j) {
      int u = t * 8 + j;
      int r = u >> 5, c = u & 31;
      sA[r * 33 + c] = x[(size_t)(brow + r) * KDIM + kt * 32 + c];
      sB[r * 33 + c] = L1[(size_t)r * KDIM + kt * 32 + c];
    }
    __syncthreads();
    for (int kk = 0; kk < 32; ++kk) {
      float a[4], b[4];
#pragma unroll
      for (int i = 0; i < 4; ++i) a[i] = sA[(tr * 4 + i) * 33 + kk];
#pragma unroll
      for (int j = 0; j < 4; ++j) b[j] = sB[(tc * 4 + j) * 33 + kk];
#pragma unroll
      for (int i = 0; i < 4; ++i)
#pragma unroll
        for (int j = 0; j < 4; ++j) acc[i][j] += a[i] * b[j];
    }
  }
#pragma unroll
  for (int i = 0; i < 4; ++i)
#pragma unroll
    for (int j = 0; j < 4; ++j)
      hid[(size_t)(brow + tr * 4 + i) * LRDIM + tc * 4 + j] = f2h(acc[i][j]);
}

// ---------------------------------------------------------------------------
// k8_main: baseline = f16(x) @ m^T via MFMA, m built on the fly during
// B-staging (frozen/gs/gb/sa fused). Fused epilogue:
//   mul = hid @ L2[0:4096]^T + scale ; add = hid @ L2[4096:8192]^T + bias
//   out = add + mul * baseline
// BM=BN=128, BK=32, 4 waves 2x2 (wave tile 64x64), dbuf LDS, 2048 blocks.
// ---------------------------------------------------------------------------
__global__ __launch_bounds__(256) void k8_main(
    const float* __restrict__ x, const void* __restrict__ frozen,
    const float* __restrict__ gs, const float* __restrict__ gb,
    const float* __restrict__ sa, const short* __restrict__ hid,
    const float* __restrict__ L2, const float* __restrict__ scale,
    const float* __restrict__ bias, const int* __restrict__ flag,
    float* __restrict__ out)
{
  __shared__ f16 sA[2][128 * 32];   // 8 KB per buf
  __shared__ f16 sB[2][128 * 32];
  int t = threadIdx.x;
  int l = t & 63, wid = t >> 6;
  int wr = wid >> 1, wc = wid & 1;
  int mode = *flag;                 // uniform

  // XCD-aware swizzle (2048 % 8 == 0 -> bijective simple form)
  int wg = blockIdx.x;
  int cpx = gridDim.x >> 3;
  int swz = (wg & 7) * cpx + (wg >> 3);
  int bm = swz & 63;                // 64 M-tiles
  int bn = swz >> 6;                // 32 N-tiles
  int brow = bm * 128, bcol = bn * 128;

  // staging assignments (constant per thread)
  int arow = t >> 1, acol = (t & 1) * 16;   // A: 16 f32 -> 16 f16
  int br0 = t >> 2, bc8 = (t & 3) * 8;      // B: 2 units, rows br0 and br0+64

  f32x4 acc[4][4] = {};

  // ---- prologue: stage kt = 0 into buf 0 ----
  {
    const float* ap = x + (size_t)(brow + arow) * KDIM + acol;
    float4 v0 = ((const float4*)ap)[0], v1 = ((const float4*)ap)[1];
    float4 v2 = ((const float4*)ap)[2], v3 = ((const float4*)ap)[3];
    *(h16x8*)&sA[0][arow * 32 + acol]     = pack8(v0, v1);
    *(h16x8*)&sA[0][arow * 32 + acol + 8] = pack8(v2, v3);
    h16x8 wb0 = build_m8(frozen, gs, gb, sa, bcol + br0,      bc8, mode);
    h16x8 wb1 = build_m8(frozen, gs, gb, sa, bcol + br0 + 64, bc8, mode);
    *(h16x8*)&sB[0][br0 * 32 + bc8]        = wb0;
    *(h16x8*)&sB[0][(br0 + 64) * 32 + bc8] = wb1;
  }

  int cur = 0;
  const int NT = KDIM / 32;         // 128
  for (int kt = 0; kt < NT; ++kt) {
    __syncthreads();                // buf[cur] staged; buf[cur^1] free
    bool pf = (kt + 1 < NT);
    h16x8 wa0, wa1, wb0, wb1;
    if (pf) {
      int k0 = (kt + 1) * 32;
      const float* ap = x + (size_t)(brow + arow) * KDIM + k0 + acol;
      float4 v0 = ((const float4*)ap)[0], v1 = ((const float4*)ap)[1];
      float4 v2 = ((const float4*)ap)[2], v3 = ((const float4*)ap)[3];
      wa0 = pack8(v0, v1);
      wa1 = pack8(v2, v3);
      wb0 = build_m8(frozen, gs, gb, sa, bcol + br0,      k0 + bc8, mode);
      wb1 = build_m8(frozen, gs, gb, sa, bcol + br0 + 64, k0 + bc8, mode);
    }
    h16x8 aF[4], bF[4];
#pragma unroll
    for (int m = 0; m < 4; ++m)
      aF[m] = *(const h16x8*)&sA[cur][(wr * 64 + m * 16 + (l & 15)) * 32 + (l >> 4) * 8];
#pragma unroll
    for (int n = 0; n < 4; ++n)
      bF[n] = *(const h16x8*)&sB[cur][(wc * 64 + n * 16 + (l & 15)) * 32 + (l >> 4) * 8];
#pragma unroll
    for (int m = 0; m < 4; ++m)
#pragma unroll
      for (int n = 0; n < 4; ++n)
        acc[m][n] = __builtin_amdgcn_mfma_f32_16x16x32_f16(aF[m], bF[n], acc[m][n], 0, 0, 0);
    if (pf) {
      *(h16x8*)&sA[cur ^ 1][arow * 32 + acol]       = wa0;
      *(h16x8*)&sA[cur ^ 1][arow * 32 + acol + 8]   = wa1;
      *(h16x8*)&sB[cur ^ 1][br0 * 32 + bc8]         = wb0;
      *(h16x8*)&sB[cur ^ 1][(br0 + 64) * 32 + bc8]  = wb1;
    }
    cur ^= 1;
  }

  // ---- fused epilogue ----
  __syncthreads();                  // all main-loop LDS reads done
  f16* sH = &sA[0][0];              // [128][64] hid tile (16 KB = both bufs)
  f16* sL = &sB[0][0];              // [128][64] L2 tile

  for (int j = 0; j < 4; ++j) {     // 1024 vec8 units each
    int u = t + j * 256;
    int r = u >> 3, c8 = (u & 7) * 8;
    *(h16x8*)&sH[r * 64 + c8] =
        *(const h16x8*)((const f16*)hid + (size_t)(brow + r) * LRDIM + c8);
    const float* lp = L2 + (size_t)(bcol + r) * LRDIM + c8;
    *(h16x8*)&sL[r * 64 + c8] = pack8(((const float4*)lp)[0], ((const float4*)lp)[1]);
  }
  __syncthreads();

  float sc[4], bi[4];
#pragma unroll
  for (int n = 0; n < 4; ++n) {
    int o = bcol + wc * 64 + n * 16 + (l & 15);
    sc[n] = scale[o];
    bi[n] = bias[o];
  }

  h16x8 hA[4][2], lB[4][2];
#pragma unroll
  for (int m = 0; m < 4; ++m)
#pragma unroll
    for (int kk = 0; kk < 2; ++kk)
      hA[m][kk] = *(const h16x8*)&sH[(wr * 64 + m * 16 + (l & 15)) * 64 + kk * 32 + (l >> 4) * 8];
#pragma unroll
  for (int n = 0; n < 4; ++n)
#pragma unroll
    for (int kk = 0; kk < 2; ++kk)
      lB[n][kk] = *(const h16x8*)&sL[(wc * 64 + n * 16 + (l & 15)) * 64 + kk * 32 + (l >> 4) * 8];

  // multiplicative: hid @ L2[0:4096]^T + scale
  f32x4 macc[4][4];
#pragma unroll
  for (int m = 0; m < 4; ++m)
#pragma unroll
    for (int n = 0; n < 4; ++n) {
      f32x4 mi = { sc[n], sc[n], sc[n], sc[n] };
      macc[m][n] = mi;
    }
#pragma unroll
  for (int kk = 0; kk < 2; ++kk)
#pragma unroll
    for (int m = 0; m < 4; ++m)
#pragma unroll
      for (int n = 0; n < 4; ++n)
        macc[m][n] = __builtin_amdgcn_mfma_f32_16x16x32_f16(hA[m][kk], lB[n][kk], macc[m][n], 0, 0, 0);
#pragma unroll
  for (int m = 0; m < 4; ++m)
#pragma unroll
    for (int n = 0; n < 4; ++n)
      acc[m][n] *= macc[m][n];      // mul * baseline

  __syncthreads();                  // lB consumed; restage add-half of L2
  for (int j = 0; j < 4; ++j) {
    int u = t + j * 256;
    int r = u >> 3, c8 = (u & 7) * 8;
    const float* lp = L2 + (size_t)(NDIM + bcol + r) * LRDIM + c8;
    *(h16x8*)&sL[r * 64 + c8] = pack8(((const float4*)lp)[0], ((const float4*)lp)[1]);
  }
  __syncthreads();

#pragma unroll
  for (int n = 0; n < 4; ++n)
#pragma unroll
    for (int kk = 0; kk < 2; ++kk)
      lB[n][kk] = *(const h16x8*)&sL[(wc * 64 + n * 16 + (l & 15)) * 64 + kk * 32 + (l >> 4) * 8];

  // additive: hid @ L2[4096:8192]^T + bias
#pragma unroll
  for (int m = 0; m < 4; ++m)
#pragma unroll
    for (int n = 0; n < 4; ++n) {
      f32x4 mi = { bi[n], bi[n], bi[n], bi[n] };
      macc[m][n] = mi;
    }
#pragma unroll
  for (int kk = 0; kk < 2; ++kk)
#pragma unroll
    for (int m = 0; m < 4; ++m)
#pragma unroll
      for (int n = 0; n < 4; ++n)
        macc[m][n] = __builtin_amdgcn_mfma_f32_16x16x32_f16(hA[m][kk], lB[n][kk], macc[m][n], 0, 0, 0);

  // out = add + mul*baseline
#pragma unroll
  for (int m = 0; m < 4; ++m) {
    int rbase = brow + wr * 64 + m * 16 + ((l >> 4) << 2);
#pragma unroll
    for (int n = 0; n < 4; ++n) {
      int c = bcol + wc * 64 + n * 16 + (l & 15);
      f32x4 v = acc[m][n] + macc[m][n];
#pragma unroll
      for (int j = 0; j < 4; ++j)
        out[(size_t)(rbase + j) * NDIM + c] = v[j];
    }
  }
}

// ---------------------------------------------------------------------------
// k7_main<false,false>: proven zero-ws fallback (in-tile m + hid recompute).
// ---------------------------------------------------------------------------
__global__ __launch_bounds__(256) void k7_main_zw(
    const float* __restrict__ x, const void* __restrict__ frozen,
    const float* __restrict__ gs, const float* __restrict__ gb,
    const float* __restrict__ sa, const float* __restrict__ L1,
    const float* __restrict__ L2, const float* __restrict__ scale,
    const float* __restrict__ bias, float* __restrict__ out)
{
  __shared__ float sA[64 * 65];
  __shared__ float sB[64 * 65];
  int t = threadIdx.x;
  int tr = t >> 4, tc = t & 15;
  int bm = blockIdx.x >> 6;
  int bn = blockIdx.x & 63;
  int brow = bm * 64, bcol = bn * 64;

  int mode = frozen_mode(frozen, t);
  float acc[4][4] = {};

  for (int kt = 0; kt < KDIM / 32; ++kt) {
    __syncthreads();
    for (int j = 0; j < 8; ++j) {
      int u = t * 8 + j;
      int r = u >> 5, c = u & 31;
      sA[r * 65 + c] = x[(size_t)(brow + r) * KDIM + kt * 32 + c];
      int o = bcol + r, i = kt * 32 + c;
      int gidx = (o >> 3) * 512 + (i >> 3);
      float fv = dec_frozen(frozen, (size_t)o * KDIM + i, mode);
      sB[r * 65 + c] = gb[gidx] + fv * gs[gidx] + sa[(size_t)o * KDIM + i];
    }
    __syncthreads();
    for (int kk = 0; kk < 32; ++kk) {
      float a[4], b[4];
#pragma unroll
      for (int i = 0; i < 4; ++i) a[i] = sA[(tr * 4 + i) * 65 + kk];
#pragma unroll
      for (int j = 0; j < 4; ++j) b[j] = sB[(tc * 4 + j) * 65 + kk];
#pragma unroll
      for (int i = 0; i < 4; ++i)
#pragma unroll
        for (int j = 0; j < 4; ++j) acc[i][j] += a[i] * b[j];
    }
  }

  float hacc[4][4] = {};
  for (int kt = 0; kt < KDIM / 32; ++kt) {
    __syncthreads();
    for (int j = 0; j < 8; ++j) {
      int u = t * 8 + j;
      int r = u >> 5, c = u & 31;
      sA[r * 65 + c] = x[(size_t)(brow + r) * KDIM + kt * 32 + c];
      sB[r * 65 + c] = L1[(size_t)r * KDIM + kt * 32 + c];
    }
    __syncthreads();
    for (int kk = 0; kk < 32; ++kk) {
      float a[4], b[4];
#pragma unroll
      for (int i = 0; i < 4; ++i) a[i] = sA[(tr * 4 + i) * 65 + kk];
#pragma unroll
      for (int j = 0; j < 4; ++j) b[j] = sB[(tc * 4 + j) * 65 + kk];
#pragma unroll
      for (int i = 0; i < 4; ++i)
#pragma unroll
        for (int j = 0; j < 4; ++j) hacc[i][j] += a[i] * b[j];
    }
  }

  __syncthreads();
#pragma unroll
  for (int i = 0; i < 4; ++i)
#pragma unroll
    for (int j = 0; j < 4; ++j)
      sA[(tr * 4 + i) * 65 + tc * 4 + j] = hacc[i][j];
  for (int j = 0; j < 16; ++j) {
    int u = t * 16 + j;
    int r = u >> 6, c = u & 63;
    sB[r * 65 + c] = L2[(size_t)(bcol + r) * LRDIM + c];
  }
  __syncthreads();

  float sc[4], bi[4];
#pragma unroll
  for (int j = 0; j < 4; ++j) {
    int o = bcol + tc * 4 + j;
    sc[j] = scale[o];
    bi[j] = bias[o];
  }

  float macc[4][4];
#pragma unroll
  for (int i = 0; i < 4; ++i)
#pragma unroll
    for (int j = 0; j < 4; ++j) macc[i][j] = sc[j];
  for (int kk = 0; kk < 64; ++kk) {
    float a[4], b[4];
#pragma unroll
    for (int i = 0; i < 4; ++i) a[i] = sA[(tr * 4 + i) * 65 + kk];
#pragma unroll
    for (int j = 0; j < 4; ++j) b[j] = sB[(tc * 4 + j) * 65 + kk];
#pragma unroll
    for (int i = 0; i < 4; ++i)
#pragma unroll
      for (int j = 0; j < 4; ++j) macc[i][j] += a[i] * b[j];
  }

  __syncthreads();
  for (int j = 0; j < 16; ++j) {
    int u = t * 16 + j;
    int r = u >> 6, c = u & 63;
    sB[r * 65 + c] = L2[(size_t)(NDIM + bcol + r) * LRDIM + c];
  }
  __syncthreads();

  float aacc[4][4];
#pragma unroll
  for (int i = 0; i < 4; ++i)
#pragma unroll
    for (int j = 0; j < 4; ++j) aacc[i][j] = bi[j];
  for (int kk = 0; kk < 64; ++kk) {
    float a[4], b[4];
#pragma unroll
    for (int i = 0; i < 4; ++i) a[i] = sA[(tr * 4 + i) * 65 + kk];
#pragma unroll
    for (int j = 0; j < 4; ++j) b[j] = sB[(tc * 4 + j) * 65 + kk];
#pragma unroll
    for (int i = 0; i < 4; ++i)
#pragma unroll
      for (int j = 0; j < 4; ++j) aacc[i][j] += a[i] * b[j];
  }

#pragma unroll
  for (int i = 0; i < 4; ++i) {
    size_t row = (size_t)(brow + tr * 4 + i);
#pragma unroll
    for (int j = 0; j < 4; ++j) {
      int col = bcol + tc * 4 + j;
      out[row * NDIM + col] = aacc[i][j] + macc[i][j] * acc[i][j];
    }
  }
}

// ---------------------------------------------------------------------------
extern "C" void kernel_launch(void* const* d_in, const int* in_sizes, int n_in,
                              void* d_out, int out_size, void* d_ws, size_t ws_size,
                              hipStream_t stream)
{
  const int SD[9] = {33554432,16777216,262144,524288,262144,262144,16777216,4096,4096};
  const int SA[9] = {4096,16777216,262144,262144,262144,524288,4096,16777216,33554432};
  bool dict = (n_in == 9), alph = (n_in == 9);
  if (n_in == 9) {
    for (int i = 0; i < 9; ++i) {
      if (in_sizes[i] != SD[i]) dict = false;
      if (in_sizes[i] != SA[i]) alph = false;
    }
  }
  if (!dict && !alph) {
    int ix = 0;
    for (int i = 0; i < n_in; ++i)
      if (in_sizes[i] == 33554432 || in_sizes[i] == 134217728) { ix = i; break; }
    dict = (ix == 0);
  }
  const float* x     = (const float*)d_in[dict ? 0 : 8];
  const void*  fr    =               d_in[1];
  const float* L1    = (const float*)d_in[dict ? 2 : 4];
  const float* L2    = (const float*)d_in[dict ? 3 : 5];
  const float* gs    = (const float*)d_in[dict ? 4 : 3];
  const float* gb    = (const float*)d_in[dict ? 5 : 2];
  const float* sa    = (const float*)d_in[dict ? 6 : 7];
  const float* scale = (const float*)d_in[dict ? 7 : 6];
  const float* bias  = (const float*)d_in[dict ? 8 : 0];
  float* out = (float*)d_out;

  const size_t HID_B = (size_t)8192 * LRDIM * 2;   // 1,048,576
  bool fast = ws_size >= HID_B + 16;

  char* ws = (char*)d_ws;
  short* hid = (short*)ws;
  int* flag  = (int*)(ws + HID_B);

  if (fast) {
    k8_flag<<<dim3(1),    dim3(256), 0, stream>>>(fr, flag);
    k7_hid<<<dim3(128),   dim3(256), 0, stream>>>(x, L1, hid);
    k8_main<<<dim3(2048), dim3(256), 0, stream>>>(
        x, fr, gs, gb, sa, hid, L2, scale, bias, flag, out);
  } else {
    k7_main_zw<<<dim3(8192), dim3(256), 0, stream>>>(
        x, fr, gs, gb, sa, L1, L2, scale, bias, out);
  }
}

// Round 9
// 813.634 us; speedup vs baseline: 6.6697x; 2.1361x over previous
//
#include <hip/hip_runtime.h>
#include <stdint.h>

typedef _Float16 f16;
typedef unsigned short u16;
typedef __attribute__((ext_vector_type(8))) _Float16 h16x8;
typedef __attribute__((ext_vector_type(8))) unsigned short u16x8;
typedef __attribute__((ext_vector_type(4))) float f32x4;

#define NDIM  4096
#define KDIM  4096
#define LRDIM 64

__device__ __forceinline__ float bf2f(u16 b) {
  union { unsigned u; float f; } c; c.u = ((unsigned)b) << 16; return c.f;
}
__device__ __forceinline__ float h2f(u16 b) {
  union { u16 u; f16 h; } c; c.u = b; return (float)c.h;
}
__device__ __forceinline__ short f2h(float v) {
  union { f16 h; short s; } c; c.h = (f16)v; return c.s;
}
__device__ __forceinline__ h16x8 pack8(float4 a, float4 b) {
  h16x8 w = { (f16)a.x, (f16)a.y, (f16)a.z, (f16)a.w,
              (f16)b.x, (f16)b.y, (f16)b.z, (f16)b.w };
  return w;
}

// ---------------------------------------------------------------------------
// frozen encoding classifier: 0 = f16 halfwords, 1 = bf16 halfwords, 2 = f32.
// All 256 threads must call before any divergence. (proven)
// ---------------------------------------------------------------------------
__device__ int frozen_mode(const void* frozen, int t) {
  const u16* fr = (const u16*)frozen;
  __shared__ int sE[256], sO[256];
  int ce = 0, co = 0;
  for (int j = 0; j < 8; ++j) {
    float ve = fabsf(bf2f(fr[t * 16 + 2 * j]));
    float vo = fabsf(bf2f(fr[t * 16 + 2 * j + 1]));
    if (ve >= 0.05f && ve <= 10.0f) ++ce;
    if (vo >= 0.05f && vo <= 10.0f) ++co;
  }
  sE[t] = ce; sO[t] = co;
  __syncthreads();
  for (int s = 128; s > 0; s >>= 1) {
    if (t < s) { sE[t] += sE[t + s]; sO[t] += sO[t + s]; }
    __syncthreads();
  }
  int te = sE[0], to = sO[0];
  __syncthreads();
  if (to > 1024) return (te > 1024) ? 1 : 2;
  return 0;
}

__device__ __forceinline__ float dec_frozen(const void* fr, size_t idx, int mode) {
  if (mode == 2) return ((const float*)fr)[idx];
  u16 b = ((const u16*)fr)[idx];
  return (mode == 1) ? bf2f(b) : h2f(b);
}

// Build 8 consecutive m elements (row o, cols i0..i0+7) as f16x8. (proven)
__device__ __forceinline__ h16x8 build_m8(
    const void* __restrict__ frozen, const float* __restrict__ gs,
    const float* __restrict__ gb, const float* __restrict__ sa,
    int o, int i0, int mode)
{
  size_t fo = (size_t)o * KDIM + i0;
  int gidx = (o >> 3) * 512 + (i0 >> 3);
  float gsf = gs[gidx], gbf = gb[gidx];
  float4 s0 = ((const float4*)(sa + fo))[0];
  float4 s1 = ((const float4*)(sa + fo))[1];
  float sv[8] = { s0.x, s0.y, s0.z, s0.w, s1.x, s1.y, s1.z, s1.w };
  float fv[8];
  if (mode == 2) {
    float4 q0 = ((const float4*)((const float*)frozen + fo))[0];
    float4 q1 = ((const float4*)((const float*)frozen + fo))[1];
    fv[0]=q0.x; fv[1]=q0.y; fv[2]=q0.z; fv[3]=q0.w;
    fv[4]=q1.x; fv[5]=q1.y; fv[6]=q1.z; fv[7]=q1.w;
  } else {
    u16x8 fb = *(const u16x8*)((const u16*)frozen + fo);
#pragma unroll
    for (int j = 0; j < 8; ++j) fv[j] = (mode == 1) ? bf2f(fb[j]) : h2f(fb[j]);
  }
  h16x8 w;
#pragma unroll
  for (int j = 0; j < 8; ++j) w[j] = (f16)(gbf + fv[j] * gsf + sv[j]);
  return w;
}

// ---------------------------------------------------------------------------
// k9_build_m: mW[o][i] (f16) = gb + dec(frozen)*gs + sa. 8192 blocks.
// ---------------------------------------------------------------------------
__global__ __launch_bounds__(256) void k9_build_m(
    const void* __restrict__ frozen, const float* __restrict__ gs,
    const float* __restrict__ gb, const float* __restrict__ sa,
    f16* __restrict__ mW)
{
  int mode = frozen_mode(frozen, threadIdx.x);
  int idx = blockIdx.x * 256 + threadIdx.x;
  int o  = idx >> 9;
  int ig = idx & 511;
  h16x8 w = build_m8(frozen, gs, gb, sa, o, ig * 8, mode);
  *(h16x8*)(mW + (size_t)o * KDIM + ig * 8) = w;
}

// ---------------------------------------------------------------------------
// k9_cast_x: x f32 -> f16. 16384 blocks.
// ---------------------------------------------------------------------------
__global__ __launch_bounds__(256) void k9_cast_x(const float* __restrict__ x,
                                                 f16* __restrict__ xh)
{
  size_t idx = (size_t)blockIdx.x * 256 + threadIdx.x;
  const float4* xp = (const float4*)x + idx * 2;
  *(h16x8*)(xh + idx * 8) = pack8(xp[0], xp[1]);
}

// ---------------------------------------------------------------------------
// k9_hid: hid[8192][64] = f16(x) @ L1^T via MFMA. BM=128, BN=64, BK=32,
// 4 waves 2x2 (wave 64x32), dbuf, 64 blocks. Reg-staged (proven patterns).
// ---------------------------------------------------------------------------
__global__ __launch_bounds__(256) void k9_hid(const float* __restrict__ x,
                                              const float* __restrict__ L1,
                                              f16* __restrict__ hid)
{
  __shared__ f16 sA[2][128 * 32];
  __shared__ f16 sB[2][64 * 32];
  int t = threadIdx.x;
  int l = t & 63, wid = t >> 6;
  int wr = wid >> 1, wc = wid & 1;
  int brow = blockIdx.x * 128;
  int arow = t >> 1, acol = (t & 1) * 16;   // A: 16 f32 per thread
  int brw = t >> 2, bc8 = (t & 3) * 8;      // B: one 8-elem unit (64 rows)

  f32x4 acc[4][2] = {};

  {
    const float* ap = x + (size_t)(brow + arow) * KDIM + acol;
    float4 v0 = ((const float4*)ap)[0], v1 = ((const float4*)ap)[1];
    float4 v2 = ((const float4*)ap)[2], v3 = ((const float4*)ap)[3];
    *(h16x8*)&sA[0][arow * 32 + acol]     = pack8(v0, v1);
    *(h16x8*)&sA[0][arow * 32 + acol + 8] = pack8(v2, v3);
    const float* lp = L1 + (size_t)brw * KDIM + bc8;
    *(h16x8*)&sB[0][brw * 32 + bc8] = pack8(((const float4*)lp)[0], ((const float4*)lp)[1]);
  }

  int cur = 0;
  const int NT = KDIM / 32;
  for (int kt = 0; kt < NT; ++kt) {
    __syncthreads();
    bool pf = (kt + 1 < NT);
    h16x8 wa0, wa1, wb;
    if (pf) {
      int k0 = (kt + 1) * 32;
      const float* ap = x + (size_t)(brow + arow) * KDIM + k0 + acol;
      float4 v0 = ((const float4*)ap)[0], v1 = ((const float4*)ap)[1];
      float4 v2 = ((const float4*)ap)[2], v3 = ((const float4*)ap)[3];
      wa0 = pack8(v0, v1); wa1 = pack8(v2, v3);
      const float* lp = L1 + (size_t)brw * KDIM + k0 + bc8;
      wb = pack8(((const float4*)lp)[0], ((const float4*)lp)[1]);
    }
    h16x8 aF[4], bF[2];
#pragma unroll
    for (int m = 0; m < 4; ++m)
      aF[m] = *(const h16x8*)&sA[cur][(wr * 64 + m * 16 + (l & 15)) * 32 + (l >> 4) * 8];
#pragma unroll
    for (int n = 0; n < 2; ++n)
      bF[n] = *(const h16x8*)&sB[cur][(wc * 32 + n * 16 + (l & 15)) * 32 + (l >> 4) * 8];
#pragma unroll
    for (int m = 0; m < 4; ++m)
#pragma unroll
      for (int n = 0; n < 2; ++n)
        acc[m][n] = __builtin_amdgcn_mfma_f32_16x16x32_f16(aF[m], bF[n], acc[m][n], 0, 0, 0);
    if (pf) {
      *(h16x8*)&sA[cur ^ 1][arow * 32 + acol]     = wa0;
      *(h16x8*)&sA[cur ^ 1][arow * 32 + acol + 8] = wa1;
      *(h16x8*)&sB[cur ^ 1][brw * 32 + bc8]       = wb;
    }
    cur ^= 1;
  }

#pragma unroll
  for (int m = 0; m < 4; ++m)
#pragma unroll
    for (int n = 0; n < 2; ++n)
#pragma unroll
      for (int j = 0; j < 4; ++j) {
        int r = wr * 64 + m * 16 + ((l >> 4) << 2) + j;
        int c = wc * 32 + n * 16 + (l & 15);
        hid[(size_t)(brow + r) * LRDIM + c] = (f16)acc[m][n][j];
      }
}

// ---------------------------------------------------------------------------
// k9_main<XH>: baseline = f16(x) @ mW^T via MFMA; A from xh (XH) or f32 x;
// B copied from precomputed mW. Fused epilogue (proven verbatim from k8).
// BM=BN=128, BK=32, 4 waves 2x2, dbuf, 2048 blocks.
// ---------------------------------------------------------------------------
template<bool XH>
__global__ __launch_bounds__(256) void k9_main(
    const float* __restrict__ x, const f16* __restrict__ xh,
    const f16* __restrict__ mW, const f16* __restrict__ hid,
    const float* __restrict__ L2, const float* __restrict__ scale,
    const float* __restrict__ bias, float* __restrict__ out)
{
  __shared__ f16 sA[2][128 * 32];
  __shared__ f16 sB[2][128 * 32];
  int t = threadIdx.x;
  int l = t & 63, wid = t >> 6;
  int wr = wid >> 1, wc = wid & 1;

  int wg = blockIdx.x;
  int cpx = gridDim.x >> 3;
  int swz = (wg & 7) * cpx + (wg >> 3);
  int bm = swz & 63;
  int bn = swz >> 6;
  int brow = bm * 128, bcol = bn * 128;

  int arow = t >> 1, acol = (t & 1) * 16;   // A from f32 x
  int ur = t >> 2, uc8 = (t & 3) * 8;       // 16B-unit rows (unit t and t+256)

  f32x4 acc[4][4] = {};

  // ---- prologue: stage kt = 0 ----
  {
    if constexpr (XH) {
      *(h16x8*)&sA[0][ur * 32 + uc8] =
          *(const h16x8*)(xh + (size_t)(brow + ur) * KDIM + uc8);
      *(h16x8*)&sA[0][(ur + 64) * 32 + uc8] =
          *(const h16x8*)(xh + (size_t)(brow + ur + 64) * KDIM + uc8);
    } else {
      const float* ap = x + (size_t)(brow + arow) * KDIM + acol;
      float4 v0 = ((const float4*)ap)[0], v1 = ((const float4*)ap)[1];
      float4 v2 = ((const float4*)ap)[2], v3 = ((const float4*)ap)[3];
      *(h16x8*)&sA[0][arow * 32 + acol]     = pack8(v0, v1);
      *(h16x8*)&sA[0][arow * 32 + acol + 8] = pack8(v2, v3);
    }
    *(h16x8*)&sB[0][ur * 32 + uc8] =
        *(const h16x8*)(mW + (size_t)(bcol + ur) * KDIM + uc8);
    *(h16x8*)&sB[0][(ur + 64) * 32 + uc8] =
        *(const h16x8*)(mW + (size_t)(bcol + ur + 64) * KDIM + uc8);
  }

  int cur = 0;
  const int NT = KDIM / 32;
  for (int kt = 0; kt < NT; ++kt) {
    __syncthreads();
    bool pf = (kt + 1 < NT);
    h16x8 wa0, wa1, wb0, wb1;
    if (pf) {
      int k0 = (kt + 1) * 32;
      if constexpr (XH) {
        wa0 = *(const h16x8*)(xh + (size_t)(brow + ur) * KDIM + k0 + uc8);
        wa1 = *(const h16x8*)(xh + (size_t)(brow + ur + 64) * KDIM + k0 + uc8);
      } else {
        const float* ap = x + (size_t)(brow + arow) * KDIM + k0 + acol;
        float4 v0 = ((const float4*)ap)[0], v1 = ((const float4*)ap)[1];
        float4 v2 = ((const float4*)ap)[2], v3 = ((const float4*)ap)[3];
        wa0 = pack8(v0, v1); wa1 = pack8(v2, v3);
      }
      wb0 = *(const h16x8*)(mW + (size_t)(bcol + ur) * KDIM + k0 + uc8);
      wb1 = *(const h16x8*)(mW + (size_t)(bcol + ur + 64) * KDIM + k0 + uc8);
    }
    h16x8 aF[4], bF[4];
#pragma unroll
    for (int m = 0; m < 4; ++m)
      aF[m] = *(const h16x8*)&sA[cur][(wr * 64 + m * 16 + (l & 15)) * 32 + (l >> 4) * 8];
#pragma unroll
    for (int n = 0; n < 4; ++n)
      bF[n] = *(const h16x8*)&sB[cur][(wc * 64 + n * 16 + (l & 15)) * 32 + (l >> 4) * 8];
#pragma unroll
    for (int m = 0; m < 4; ++m)
#pragma unroll
      for (int n = 0; n < 4; ++n)
        acc[m][n] = __builtin_amdgcn_mfma_f32_16x16x32_f16(aF[m], bF[n], acc[m][n], 0, 0, 0);
    if (pf) {
      if constexpr (XH) {
        *(h16x8*)&sA[cur ^ 1][ur * 32 + uc8]        = wa0;
        *(h16x8*)&sA[cur ^ 1][(ur + 64) * 32 + uc8] = wa1;
      } else {
        *(h16x8*)&sA[cur ^ 1][arow * 32 + acol]     = wa0;
        *(h16x8*)&sA[cur ^ 1][arow * 32 + acol + 8] = wa1;
      }
      *(h16x8*)&sB[cur ^ 1][ur * 32 + uc8]        = wb0;
      *(h16x8*)&sB[cur ^ 1][(ur + 64) * 32 + uc8] = wb1;
    }
    cur ^= 1;
  }

  // ---- fused epilogue (verbatim k8, proven) ----
  __syncthreads();
  f16* sH = &sA[0][0];
  f16* sL = &sB[0][0];

  for (int j = 0; j < 4; ++j) {
    int u = t + j * 256;
    int r = u >> 3, c8 = (u & 7) * 8;
    *(h16x8*)&sH[r * 64 + c8] =
        *(const h16x8*)(hid + (size_t)(brow + r) * LRDIM + c8);
    const float* lp = L2 + (size_t)(bcol + r) * LRDIM + c8;
    *(h16x8*)&sL[r * 64 + c8] = pack8(((const float4*)lp)[0], ((const float4*)lp)[1]);
  }
  __syncthreads();

  float sc[4], bi[4];
#pragma unroll
  for (int n = 0; n < 4; ++n) {
    int o = bcol + wc * 64 + n * 16 + (l & 15);
    sc[n] = scale[o];
    bi[n] = bias[o];
  }

  h16x8 hA[4][2], lB[4][2];
#pragma unroll
  for (int m = 0; m < 4; ++m)
#pragma unroll
    for (int kk = 0; kk < 2; ++kk)
      hA[m][kk] = *(const h16x8*)&sH[(wr * 64 + m * 16 + (l & 15)) * 64 + kk * 32 + (l >> 4) * 8];
#pragma unroll
  for (int n = 0; n < 4; ++n)
#pragma unroll
    for (int kk = 0; kk < 2; ++kk)
      lB[n][kk] = *(const h16x8*)&sL[(wc * 64 + n * 16 + (l & 15)) * 64 + kk * 32 + (l >> 4) * 8];

  f32x4 macc[4][4];
#pragma unroll
  for (int m = 0; m < 4; ++m)
#pragma unroll
    for (int n = 0; n < 4; ++n) {
      f32x4 mi = { sc[n], sc[n], sc[n], sc[n] };
      macc[m][n] = mi;
    }
#pragma unroll
  for (int kk = 0; kk < 2; ++kk)
#pragma unroll
    for (int m = 0; m < 4; ++m)
#pragma unroll
      for (int n = 0; n < 4; ++n)
        macc[m][n] = __builtin_amdgcn_mfma_f32_16x16x32_f16(hA[m][kk], lB[n][kk], macc[m][n], 0, 0, 0);
#pragma unroll
  for (int m = 0; m < 4; ++m)
#pragma unroll
    for (int n = 0; n < 4; ++n)
      acc[m][n] *= macc[m][n];

  __syncthreads();
  for (int j = 0; j < 4; ++j) {
    int u = t + j * 256;
    int r = u >> 3, c8 = (u & 7) * 8;
    const float* lp = L2 + (size_t)(NDIM + bcol + r) * LRDIM + c8;
    *(h16x8*)&sL[r * 64 + c8] = pack8(((const float4*)lp)[0], ((const float4*)lp)[1]);
  }
  __syncthreads();

#pragma unroll
  for (int n = 0; n < 4; ++n)
#pragma unroll
    for (int kk = 0; kk < 2; ++kk)
      lB[n][kk] = *(const h16x8*)&sL[(wc * 64 + n * 16 + (l & 15)) * 64 + kk * 32 + (l >> 4) * 8];

#pragma unroll
  for (int m = 0; m < 4; ++m)
#pragma unroll
    for (int n = 0; n < 4; ++n) {
      f32x4 mi = { bi[n], bi[n], bi[n], bi[n] };
      macc[m][n] = mi;
    }
#pragma unroll
  for (int kk = 0; kk < 2; ++kk)
#pragma unroll
    for (int m = 0; m < 4; ++m)
#pragma unroll
      for (int n = 0; n < 4; ++n)
        macc[m][n] = __builtin_amdgcn_mfma_f32_16x16x32_f16(hA[m][kk], lB[n][kk], macc[m][n], 0, 0, 0);

#pragma unroll
  for (int m = 0; m < 4; ++m) {
    int rbase = brow + wr * 64 + m * 16 + ((l >> 4) << 2);
#pragma unroll
    for (int n = 0; n < 4; ++n) {
      int c = bcol + wc * 64 + n * 16 + (l & 15);
      f32x4 v = acc[m][n] + macc[m][n];
#pragma unroll
      for (int j = 0; j < 4; ++j)
        out[(size_t)(rbase + j) * NDIM + c] = v[j];
    }
  }
}

// ---------------------------------------------------------------------------
// T0 fallback: round-8 proven kernels, unchanged.
// ---------------------------------------------------------------------------
__global__ __launch_bounds__(256) void k8_flag(const void* __restrict__ fr,
                                               int* __restrict__ flag)
{
  int m = frozen_mode(fr, threadIdx.x);
  if (threadIdx.x == 0) *flag = m;
}

__global__ __launch_bounds__(256) void k7_hid(const float* __restrict__ x,
                                              const float* __restrict__ L1,
                                              short* __restrict__ hid)
{
  __shared__ float sA[64 * 33];
  __shared__ float sB[64 * 33];
  int t = threadIdx.x;
  int brow = blockIdx.x * 64;
  int tr = t >> 4, tc = t & 15;
  float acc[4][4] = {};
  for (int kt = 0; kt < KDIM / 32; ++kt) {
    __syncthreads();
    for (int j = 0; j < 8; ++j) {
      int u = t * 8 + j;
      int r = u >> 5, c = u & 31;
      sA[r * 33 + c] = x[(size_t)(brow + r) * KDIM + kt * 32 + c];
      sB[r * 33 + c] = L1[(size_t)r * KDIM + kt * 32 + c];
    }
    __syncthreads();
    for (int kk = 0; kk < 32; ++kk) {
      float a[4], b[4];
#pragma unroll
      for (int i = 0; i < 4; ++i) a[i] = sA[(tr * 4 + i) * 33 + kk];
#pragma unroll
      for (int j = 0; j < 4; ++j) b[j] = sB[(tc * 4 + j) * 33 + kk];
#pragma unroll
      for (int i = 0; i < 4; ++i)
#pragma unroll
        for (int j = 0; j < 4; ++j) acc[i][j] += a[i] * b[j];
    }
  }
#pragma unroll
  for (int i = 0; i < 4; ++i)
#pragma unroll
    for (int j = 0; j < 4; ++j)
      hid[(size_t)(brow + tr * 4 + i) * LRDIM + tc * 4 + j] = f2h(acc[i][j]);
}

__global__ __launch_bounds__(256) void k8_main(
    const float* __restrict__ x, const void* __restrict__ frozen,
    const float* __restrict__ gs, const float* __restrict__ gb,
    const float* __restrict__ sa, const short* __restrict__ hid,
    const float* __restrict__ L2, const float* __restrict__ scale,
    const float* __restrict__ bias, const int* __restrict__ flag,
    float* __restrict__ out)
{
  __shared__ f16 sA[2][128 * 32];
  __shared__ f16 sB[2][128 * 32];
  int t = threadIdx.x;
  int l = t & 63, wid = t >> 6;
  int wr = wid >> 1, wc = wid & 1;
  int mode = *flag;

  int wg = blockIdx.x;
  int cpx = gridDim.x >> 3;
  int swz = (wg & 7) * cpx + (wg >> 3);
  int bm = swz & 63;
  int bn = swz >> 6;
  int brow = bm * 128, bcol = bn * 128;

  int arow = t >> 1, acol = (t & 1) * 16;
  int br0 = t >> 2, bc8 = (t & 3) * 8;

  f32x4 acc[4][4] = {};
  {
    const float* ap = x + (size_t)(brow + arow) * KDIM + acol;
    float4 v0 = ((const float4*)ap)[0], v1 = ((const float4*)ap)[1];
    float4 v2 = ((const float4*)ap)[2], v3 = ((const float4*)ap)[3];
    *(h16x8*)&sA[0][arow * 32 + acol]     = pack8(v0, v1);
    *(h16x8*)&sA[0][arow * 32 + acol + 8] = pack8(v2, v3);
    h16x8 wb0 = build_m8(frozen, gs, gb, sa, bcol + br0,      bc8, mode);
    h16x8 wb1 = build_m8(frozen, gs, gb, sa, bcol + br0 + 64, bc8, mode);
    *(h16x8*)&sB[0][br0 * 32 + bc8]        = wb0;
    *(h16x8*)&sB[0][(br0 + 64) * 32 + bc8] = wb1;
  }

  int cur = 0;
  const int NT = KDIM / 32;
  for (int kt = 0; kt < NT; ++kt) {
    __syncthreads();
    bool pf = (kt + 1 < NT);
    h16x8 wa0, wa1, wb0, wb1;
    if (pf) {
      int k0 = (kt + 1) * 32;
      const float* ap = x + (size_t)(brow + arow) * KDIM + k0 + acol;
      float4 v0 = ((const float4*)ap)[0], v1 = ((const float4*)ap)[1];
      float4 v2 = ((const float4*)ap)[2], v3 = ((const float4*)ap)[3];
      wa0 = pack8(v0, v1); wa1 = pack8(v2, v3);
      wb0 = build_m8(frozen, gs, gb, sa, bcol + br0,      k0 + bc8, mode);
      wb1 = build_m8(frozen, gs, gb, sa, bcol + br0 + 64, k0 + bc8, mode);
    }
    h16x8 aF[4], bF[4];
#pragma unroll
    for (int m = 0; m < 4; ++m)
      aF[m] = *(const h16x8*)&sA[cur][(wr * 64 + m * 16 + (l & 15)) * 32 + (l >> 4) * 8];
#pragma unroll
    for (int n = 0; n < 4; ++n)
      bF[n] = *(const h16x8*)&sB[cur][(wc * 64 + n * 16 + (l & 15)) * 32 + (l >> 4) * 8];
#pragma unroll
    for (int m = 0; m < 4; ++m)
#pragma unroll
      for (int n = 0; n < 4; ++n)
        acc[m][n] = __builtin_amdgcn_mfma_f32_16x16x32_f16(aF[m], bF[n], acc[m][n], 0, 0, 0);
    if (pf) {
      *(h16x8*)&sA[cur ^ 1][arow * 32 + acol]       = wa0;
      *(h16x8*)&sA[cur ^ 1][arow * 32 + acol + 8]   = wa1;
      *(h16x8*)&sB[cur ^ 1][br0 * 32 + bc8]         = wb0;
      *(h16x8*)&sB[cur ^ 1][(br0 + 64) * 32 + bc8]  = wb1;
    }
    cur ^= 1;
  }

  __syncthreads();
  f16* sH = &sA[0][0];
  f16* sL = &sB[0][0];
  for (int j = 0; j < 4; ++j) {
    int u = t + j * 256;
    int r = u >> 3, c8 = (u & 7) * 8;
    *(h16x8*)&sH[r * 64 + c8] =
        *(const h16x8*)((const f16*)hid + (size_t)(brow + r) * LRDIM + c8);
    const float* lp = L2 + (size_t)(bcol + r) * LRDIM + c8;
    *(h16x8*)&sL[r * 64 + c8] = pack8(((const float4*)lp)[0], ((const float4*)lp)[1]);
  }
  __syncthreads();

  float sc[4], bi[4];
#pragma unroll
  for (int n = 0; n < 4; ++n) {
    int o = bcol + wc * 64 + n * 16 + (l & 15);
    sc[n] = scale[o];
    bi[n] = bias[o];
  }

  h16x8 hA[4][2], lB[4][2];
#pragma unroll
  for (int m = 0; m < 4; ++m)
#pragma unroll
    for (int kk = 0; kk < 2; ++kk)
      hA[m][kk] = *(const h16x8*)&sH[(wr * 64 + m * 16 + (l & 15)) * 64 + kk * 32 + (l >> 4) * 8];
#pragma unroll
  for (int n = 0; n < 4; ++n)
#pragma unroll
    for (int kk = 0; kk < 2; ++kk)
      lB[n][kk] = *(const h16x8*)&sL[(wc * 64 + n * 16 + (l & 15)) * 64 + kk * 32 + (l >> 4) * 8];

  f32x4 macc[4][4];
#pragma unroll
  for (int m = 0; m < 4; ++m)
#pragma unroll
    for (int n = 0; n < 4; ++n) {
      f32x4 mi = { sc[n], sc[n], sc[n], sc[n] };
      macc[m][n] = mi;
    }
#pragma unroll
  for (int kk = 0; kk < 2; ++kk)
#pragma unroll
    for (int m = 0; m < 4; ++m)
#pragma unroll
      for (int n = 0; n < 4; ++n)
        macc[m][n] = __builtin_amdgcn_mfma_f32_16x16x32_f16(hA[m][kk], lB[n][kk], macc[m][n], 0, 0, 0);
#pragma unroll
  for (int m = 0; m < 4; ++m)
#pragma unroll
    for (int n = 0; n < 4; ++n)
      acc[m][n] *= macc[m][n];

  __syncthreads();
  for (int j = 0; j < 4; ++j) {
    int u = t + j * 256;
    int r = u >> 3, c8 = (u & 7) * 8;
    const float* lp = L2 + (size_t)(NDIM + bcol + r) * LRDIM + c8;
    *(h16x8*)&sL[r * 64 + c8] = pack8(((const float4*)lp)[0], ((const float4*)lp)[1]);
  }
  __syncthreads();

#pragma unroll
  for (int n = 0; n < 4; ++n)
#pragma unroll
    for (int kk = 0; kk < 2; ++kk)
      lB[n][kk] = *(const h16x8*)&sL[(wc * 64 + n * 16 + (l & 15)) * 64 + kk * 32 + (l >> 4) * 8];

#pragma unroll
  for (int m = 0; m < 4; ++m)
#pragma unroll
    for (int n = 0; n < 4; ++n) {
      f32x4 mi = { bi[n], bi[n], bi[n], bi[n] };
      macc[m][n] = mi;
    }
#pragma unroll
  for (int kk = 0; kk < 2; ++kk)
#pragma unroll
    for (int m = 0; m < 4; ++m)
#pragma unroll
      for (int n = 0; n < 4; ++n)
        macc[m][n] = __builtin_amdgcn_mfma_f32_16x16x32_f16(hA[m][kk], lB[n][kk], macc[m][n], 0, 0, 0);

#pragma unroll
  for (int m = 0; m < 4; ++m) {
    int rbase = brow + wr * 64 + m * 16 + ((l >> 4) << 2);
#pragma unroll
    for (int n = 0; n < 4; ++n) {
      int c = bcol + wc * 64 + n * 16 + (l & 15);
      f32x4 v = acc[m][n] + macc[m][n];
#pragma unroll
      for (int j = 0; j < 4; ++j)
        out[(size_t)(rbase + j) * NDIM + c] = v[j];
    }
  }
}

// zero-ws ultimate fallback (proven round 7)
__global__ __launch_bounds__(256) void k7_main_zw(
    const float* __restrict__ x, const void* __restrict__ frozen,
    const float* __restrict__ gs, const float* __restrict__ gb,
    const float* __restrict__ sa, const float* __restrict__ L1,
    const float* __restrict__ L2, const float* __restrict__ scale,
    const float* __restrict__ bias, float* __restrict__ out)
{
  __shared__ float sA[64 * 65];
  __shared__ float sB[64 * 65];
  int t = threadIdx.x;
  int tr = t >> 4, tc = t & 15;
  int bm = blockIdx.x >> 6;
  int bn = blockIdx.x & 63;
  int brow = bm * 64, bcol = bn * 64;
  int mode = frozen_mode(frozen, t);
  float acc[4][4] = {};
  for (int kt = 0; kt < KDIM / 32; ++kt) {
    __syncthreads();
    for (int j = 0; j < 8; ++j) {
      int u = t * 8 + j;
      int r = u >> 5, c = u & 31;
      sA[r * 65 + c] = x[(size_t)(brow + r) * KDIM + kt * 32 + c];
      int o = bcol + r, i = kt * 32 + c;
      int gidx = (o >> 3) * 512 + (i >> 3);
      float fv = dec_frozen(frozen, (size_t)o * KDIM + i, mode);
      sB[r * 65 + c] = gb[gidx] + fv * gs[gidx] + sa[(size_t)o * KDIM + i];
    }
    __syncthreads();
    for (int kk = 0; kk < 32; ++kk) {
      float a[4], b[4];
#pragma unroll
      for (int i = 0; i < 4; ++i) a[i] = sA[(tr * 4 + i) * 65 + kk];
#pragma unroll
      for (int j = 0; j < 4; ++j) b[j] = sB[(tc * 4 + j) * 65 + kk];
#pragma unroll
      for (int i = 0; i < 4; ++i)
#pragma unroll
        for (int j = 0; j < 4; ++j) acc[i][j] += a[i] * b[j];
    }
  }
  float hacc[4][4] = {};
  for (int kt = 0; kt < KDIM / 32; ++kt) {
    __syncthreads();
    for (int j = 0; j < 8; ++j) {
      int u = t * 8 + j;
      int r = u >> 5, c = u & 31;
      sA[r * 65 + c] = x[(size_t)(brow + r) * KDIM + kt * 32 + c];
      sB[r * 65 + c] = L1[(size_t)r * KDIM + kt * 32 + c];
    }
    __syncthreads();
    for (int kk = 0; kk < 32; ++kk) {
      float a[4], b[4];
#pragma unroll
      for (int i = 0; i < 4; ++i) a[i] = sA[(tr * 4 + i) * 65 + kk];
#pragma unroll
      for (int j = 0; j < 4; ++j) b[j] = sB[(tc * 4 + j) * 65 + kk];
#pragma unroll
      for (int i = 0; i < 4; ++i)
#pragma unroll
        for (int j = 0; j < 4; ++j) hacc[i][j] += a[i] * b[j];
    }
  }
  __syncthreads();
#pragma unroll
  for (int i = 0; i < 4; ++i)
#pragma unroll
    for (int j = 0; j < 4; ++j)
      sA[(tr * 4 + i) * 65 + tc * 4 + j] = hacc[i][j];
  for (int j = 0; j < 16; ++j) {
    int u = t * 16 + j;
    int r = u >> 6, c = u & 63;
    sB[r * 65 + c] = L2[(size_t)(bcol + r) * LRDIM + c];
  }
  __syncthreads();
  float sc[4], bi[4];
#pragma unroll
  for (int j = 0; j < 4; ++j) {
    int o = bcol + tc * 4 + j;
    sc[j] = scale[o];
    bi[j] = bias[o];
  }
  float macc[4][4];
#pragma unroll
  for (int i = 0; i < 4; ++i)
#pragma unroll
    for (int j = 0; j < 4; ++j) macc[i][j] = sc[j];
  for (int kk = 0; kk < 64; ++kk) {
    float a[4], b[4];
#pragma unroll
    for (int i = 0; i < 4; ++i) a[i] = sA[(tr * 4 + i) * 65 + kk];
#pragma unroll
    for (int j = 0; j < 4; ++j) b[j] = sB[(tc * 4 + j) * 65 + kk];
#pragma unroll
    for (int i = 0; i < 4; ++i)
#pragma unroll
      for (int j = 0; j < 4; ++j) macc[i][j] += a[i] * b[j];
  }
  __syncthreads();
  for (int j = 0; j < 16; ++j) {
    int u = t * 16 + j;
    int r = u >> 6, c = u & 63;
    sB[r * 65 + c] = L2[(size_t)(NDIM + bcol + r) * LRDIM + c];
  }
  __syncthreads();
  float aacc[4][4];
#pragma unroll
  for (int i = 0; i < 4; ++i)
#pragma unroll
    for (int j = 0; j < 4; ++j) aacc[i][j] = bi[j];
  for (int kk = 0; kk < 64; ++kk) {
    float a[4], b[4];
#pragma unroll
    for (int i = 0; i < 4; ++i) a[i] = sA[(tr * 4 + i) * 65 + kk];
#pragma unroll
    for (int j = 0; j < 4; ++j) b[j] = sB[(tc * 4 + j) * 65 + kk];
#pragma unroll
    for (int i = 0; i < 4; ++i)
#pragma unroll
      for (int j = 0; j < 4; ++j) aacc[i][j] += a[i] * b[j];
  }
#pragma unroll
  for (int i = 0; i < 4; ++i) {
    size_t row = (size_t)(brow + tr * 4 + i);
#pragma unroll
    for (int j = 0; j < 4; ++j) {
      int col = bcol + tc * 4 + j;
      out[row * NDIM + col] = aacc[i][j] + macc[i][j] * acc[i][j];
    }
  }
}

// ---------------------------------------------------------------------------
extern "C" void kernel_launch(void* const* d_in, const int* in_sizes, int n_in,
                              void* d_out, int out_size, void* d_ws, size_t ws_size,
                              hipStream_t stream)
{
  const int SD[9] = {33554432,16777216,262144,524288,262144,262144,16777216,4096,4096};
  const int SA[9] = {4096,16777216,262144,262144,262144,524288,4096,16777216,33554432};
  bool dict = (n_in == 9), alph = (n_in == 9);
  if (n_in == 9) {
    for (int i = 0; i < 9; ++i) {
      if (in_sizes[i] != SD[i]) dict = false;
      if (in_sizes[i] != SA[i]) alph = false;
    }
  }
  if (!dict && !alph) {
    int ix = 0;
    for (int i = 0; i < n_in; ++i)
      if (in_sizes[i] == 33554432 || in_sizes[i] == 134217728) { ix = i; break; }
    dict = (ix == 0);
  }
  const float* x     = (const float*)d_in[dict ? 0 : 8];
  const void*  fr    =               d_in[1];
  const float* L1    = (const float*)d_in[dict ? 2 : 4];
  const float* L2    = (const float*)d_in[dict ? 3 : 5];
  const float* gs    = (const float*)d_in[dict ? 4 : 3];
  const float* gb    = (const float*)d_in[dict ? 5 : 2];
  const float* sa    = (const float*)d_in[dict ? 6 : 7];
  const float* scale = (const float*)d_in[dict ? 7 : 6];
  const float* bias  = (const float*)d_in[dict ? 8 : 0];
  float* out = (float*)d_out;

  const size_t MW_B  = (size_t)NDIM * KDIM * 2;    // 33,554,432
  const size_t XH_B  = (size_t)8192 * KDIM * 2;    // 67,108,864
  const size_t HID_B = (size_t)8192 * LRDIM * 2;   //  1,048,576

  char* ws = (char*)d_ws;

  if (ws_size >= MW_B + XH_B + HID_B + 64) {
    // T2: mW + f16 x + hid
    f16* mW  = (f16*)ws;
    f16* xh  = (f16*)(ws + MW_B);
    f16* hid = (f16*)(ws + MW_B + XH_B);
    k9_build_m<<<dim3(8192), dim3(256), 0, stream>>>(fr, gs, gb, sa, mW);
    k9_cast_x<<<dim3(16384), dim3(256), 0, stream>>>(x, xh);
    k9_hid<<<dim3(64), dim3(256), 0, stream>>>(x, L1, hid);
    k9_main<true><<<dim3(2048), dim3(256), 0, stream>>>(
        x, xh, mW, hid, L2, scale, bias, out);
  } else if (ws_size >= MW_B + HID_B + 64) {
    // T1: mW + hid; A staged from f32 x
    f16* mW  = (f16*)ws;
    f16* hid = (f16*)(ws + MW_B);
    k9_build_m<<<dim3(8192), dim3(256), 0, stream>>>(fr, gs, gb, sa, mW);
    k9_hid<<<dim3(64), dim3(256), 0, stream>>>(x, L1, hid);
    k9_main<false><<<dim3(2048), dim3(256), 0, stream>>>(
        x, nullptr, mW, hid, L2, scale, bias, out);
  } else if (ws_size >= HID_B + 16) {
    // T0: round-8 proven path
    short* hid = (short*)ws;
    int* flag  = (int*)(ws + HID_B);
    k8_flag<<<dim3(1),    dim3(256), 0, stream>>>(fr, flag);
    k7_hid<<<dim3(128),   dim3(256), 0, stream>>>(x, L1, hid);
    k8_main<<<dim3(2048), dim3(256), 0, stream>>>(
        x, fr, gs, gb, sa, (const short*)hid, L2, scale, bias, flag, out);
  } else {
    k7_main_zw<<<dim3(8192), dim3(256), 0, stream>>>(
        x, fr, gs, gb, sa, L1, L2, scale, bias, out);
  }
}